// Round 1
// baseline (181.869 us; speedup 1.0000x reference)
//
#include <hip/hip_runtime.h>
#include <math.h>

#define LEN 4096
#define NSTATE 64

__device__ inline float2 cmulf(float2 a, float2 b){
  return make_float2(a.x*b.x - a.y*b.y, a.x*b.y + a.y*b.x);
}

// ---------------- Setup kernel 1: K[k] via DPLR Cauchy sums (double precision) ----------------
__global__ void s4_kernelA1(const float* __restrict__ Lre, const float* __restrict__ Lim,
                            const float* __restrict__ Pre, const float* __restrict__ Pim,
                            const float* __restrict__ Bre, const float* __restrict__ Bim,
                            const float* __restrict__ Cre, const float* __restrict__ Cim,
                            float2* __restrict__ Kout) {
  int k = blockIdx.x * blockDim.x + threadIdx.x;
  if (k >= LEN) return;
  double ang = -2.0 * M_PI * (double)k / (double)LEN;
  double orr = cos(ang), oi = sin(ang);
  // 1+Omega, 1-Omega
  double dr = 1.0 + orr, di = oi;
  double d2 = dr*dr + di*di;
  double nr = 1.0 - orr, ni = -oi;
  // g = (2/step) * (1-O)/(1+O), step=0.001
  double gr = 2000.0 * (nr*dr + ni*di) / d2;
  double gi = 2000.0 * (ni*dr - nr*di) / d2;
  // c = 2/(1+O)
  double cr = 2.0 * dr / d2, ci = -2.0 * di / d2;
  double k00r=0,k00i=0,k01r=0,k01i=0,k10r=0,k10i=0,k11r=0,k11i=0;
  for (int n = 0; n < NSTATE; ++n) {
    double lr = Lre[n], li = Lim[n];
    double pr = Pre[n], pi = Pim[n];
    double br = Bre[n], bi = Bim[n];
    double qr = Cre[n], qi = Cim[n];
    double er = gr - lr, ei = gi - li;
    double e2 = er*er + ei*ei;
    double den_r = er / e2, den_i = -ei / e2;       // 1/(g-Lambda)
    // conj(C)*B, conj(C)*P, conj(P)*B, conj(P)*P
    double cbr = qr*br + qi*bi, cbi = qr*bi - qi*br;
    double cpr = qr*pr + qi*pi, cpi = qr*pi - qi*pr;
    double pbr = pr*br + pi*bi, pbi = pr*bi - pi*br;
    double ppr = pr*pr + pi*pi;
    k00r += den_r*cbr - den_i*cbi; k00i += den_r*cbi + den_i*cbr;
    k01r += den_r*cpr - den_i*cpi; k01i += den_r*cpi + den_i*cpr;
    k10r += den_r*pbr - den_i*pbi; k10i += den_r*pbi + den_i*pbr;
    k11r += den_r*ppr;             k11i += den_i*ppr;
  }
  // K = c * (k00 - k01 * k10 / (1 + k11))
  double ar = 1.0 + k11r, ai = k11i;
  double a2 = ar*ar + ai*ai;
  double ivr = ar/a2, ivi = -ai/a2;
  double mr = k01r*k10r - k01i*k10i, mi = k01r*k10i + k01i*k10r;
  double tr = mr*ivr - mi*ivi, ti = mr*ivi + mi*ivr;
  double sr = k00r - tr, si = k00i - ti;
  double Kr = cr*sr - ci*si, Ki = cr*si + ci*sr;
  Kout[k] = make_float2((float)Kr, (float)Ki);
}

// ---------------- Setup kernel 2: Hermitian-symmetrize, scale by 1/L, base-4 digit-reverse ----------------
__global__ void s4_kernelA2(const float2* __restrict__ Kin, float2* __restrict__ keff_br) {
  int p = blockIdx.x * blockDim.x + threadIdx.x;
  if (p >= LEN) return;
  int k = 0, pp = p;
  #pragma unroll
  for (int i = 0; i < 6; ++i) { k = (k << 2) | (pp & 3); pp >>= 2; }
  int kneg = (LEN - k) & (LEN - 1);
  float2 a = Kin[k], b = Kin[kneg];
  // Keff = (K[k] + conj(K[L-k])) / 2, scaled by 1/L
  const float s = 0.5f / (float)LEN;
  keff_br[p] = make_float2(s * (a.x + b.x), s * (a.y - b.y));
}

// ---------------- Main kernel: per row-pair, fwd FFT (DIF r4) -> multiply -> inv FFT (DIT r4) ----------------
__launch_bounds__(256)
__global__ void s4_fftconv(const float* __restrict__ x, const float2* __restrict__ keff_br,
                           float* __restrict__ out) {
  __shared__ float2 X[LEN];
  const int t = threadIdx.x;
  const size_t base = (size_t)blockIdx.x * 2 * LEN;
  const float* x1 = x + base;
  const float* x2 = x1 + LEN;

  #pragma unroll
  for (int i = 0; i < 16; ++i) {
    int idx = t + 256*i;
    X[idx] = make_float2(x1[idx], x2[idx]);
  }
  __syncthreads();

  // forward DIF radix-4: natural order in -> base-4 digit-reversed out
  for (int n = LEN; n >= 4; n >>= 2) {
    const int q = n >> 2;
    const float fac = -6.28318530717958647692f / (float)n;
    #pragma unroll
    for (int it = 0; it < 4; ++it) {
      int m = t + 256*it;
      int j = m & (q - 1);
      int i0 = 4*m - 3*j;            // = block_base + j
      float2 a0 = X[i0], a1 = X[i0+q], a2 = X[i0+2*q], a3 = X[i0+3*q];
      float2 t0 = make_float2(a0.x+a2.x, a0.y+a2.y);
      float2 t1 = make_float2(a0.x-a2.x, a0.y-a2.y);
      float2 t2 = make_float2(a1.x+a3.x, a1.y+a3.y);
      float2 t3 = make_float2(a1.x-a3.x, a1.y-a3.y);
      float2 y0 = make_float2(t0.x+t2.x, t0.y+t2.y);
      float2 y1 = make_float2(t1.x+t3.y, t1.y-t3.x);  // t1 - i*t3
      float2 y2 = make_float2(t0.x-t2.x, t0.y-t2.y);
      float2 y3 = make_float2(t1.x-t3.y, t1.y+t3.x);  // t1 + i*t3
      float ang = fac * (float)j;
      float s1, c1;
      __sincosf(ang, &s1, &c1);
      float2 w1 = make_float2(c1, s1);
      float2 w2 = cmulf(w1, w1);
      float2 w3 = cmulf(w2, w1);
      X[i0]     = y0;
      X[i0+q]   = cmulf(y1, w1);
      X[i0+2*q] = cmulf(y2, w2);
      X[i0+3*q] = cmulf(y3, w3);
    }
    __syncthreads();
  }

  // pointwise multiply by Keff/L (digit-reversed order), fused with first inverse stage (n=4: j=0, w=1)
  #pragma unroll
  for (int it = 0; it < 4; ++it) {
    int m = t + 256*it;
    int i0 = 4*m;
    float2 u0 = cmulf(X[i0],   keff_br[i0]);
    float2 u1 = cmulf(X[i0+1], keff_br[i0+1]);
    float2 u2 = cmulf(X[i0+2], keff_br[i0+2]);
    float2 u3 = cmulf(X[i0+3], keff_br[i0+3]);
    float2 t0 = make_float2(u0.x+u2.x, u0.y+u2.y);
    float2 t1 = make_float2(u0.x-u2.x, u0.y-u2.y);
    float2 t2 = make_float2(u1.x+u3.x, u1.y+u3.y);
    float2 t3 = make_float2(u1.x-u3.x, u1.y-u3.y);
    X[i0]   = make_float2(t0.x+t2.x, t0.y+t2.y);   // a0
    X[i0+1] = make_float2(t1.x-t3.y, t1.y+t3.x);   // a1 = t1 + i*t3
    X[i0+2] = make_float2(t0.x-t2.x, t0.y-t2.y);   // a2
    X[i0+3] = make_float2(t1.x+t3.y, t1.y-t3.x);   // a3 = t1 - i*t3
  }
  __syncthreads();

  // remaining inverse DIT radix-4 stages: digit-reversed in -> natural out (un-normalized; 1/L folded into keff)
  for (int n = 16; n <= LEN; n <<= 2) {
    const int q = n >> 2;
    const float fac = 6.28318530717958647692f / (float)n;
    #pragma unroll
    for (int it = 0; it < 4; ++it) {
      int m = t + 256*it;
      int j = m & (q - 1);
      int i0 = 4*m - 3*j;
      float ang = fac * (float)j;
      float s1, c1;
      __sincosf(ang, &s1, &c1);
      float2 w1 = make_float2(c1, s1);
      float2 w2 = cmulf(w1, w1);
      float2 w3 = cmulf(w2, w1);
      float2 u0 = X[i0];
      float2 u1 = cmulf(X[i0+q],   w1);
      float2 u2 = cmulf(X[i0+2*q], w2);
      float2 u3 = cmulf(X[i0+3*q], w3);
      float2 t0 = make_float2(u0.x+u2.x, u0.y+u2.y);
      float2 t1 = make_float2(u0.x-u2.x, u0.y-u2.y);
      float2 t2 = make_float2(u1.x+u3.x, u1.y+u3.y);
      float2 t3 = make_float2(u1.x-u3.x, u1.y-u3.y);
      X[i0]     = make_float2(t0.x+t2.x, t0.y+t2.y);
      X[i0+q]   = make_float2(t1.x-t3.y, t1.y+t3.x);  // t1 + i*t3
      X[i0+2*q] = make_float2(t0.x-t2.x, t0.y-t2.y);
      X[i0+3*q] = make_float2(t1.x+t3.y, t1.y-t3.x);  // t1 - i*t3
    }
    __syncthreads();
  }

  float* o1 = out + base;
  float* o2 = o1 + LEN;
  #pragma unroll
  for (int i = 0; i < 16; ++i) {
    int idx = t + 256*i;
    float2 v = X[idx];
    o1[idx] = v.x;   // row 2b   (real part)
    o2[idx] = v.y;   // row 2b+1 (imag part)
  }
}

extern "C" void kernel_launch(void* const* d_in, const int* in_sizes, int n_in,
                              void* d_out, int out_size, void* d_ws, size_t ws_size,
                              hipStream_t stream) {
  const float* x   = (const float*)d_in[0];
  const float* Lre = (const float*)d_in[1];
  const float* Lim = (const float*)d_in[2];
  const float* Pre = (const float*)d_in[3];
  const float* Pim = (const float*)d_in[4];
  const float* Bre = (const float*)d_in[5];
  const float* Bim = (const float*)d_in[6];
  const float* Cre = (const float*)d_in[7];
  const float* Cim = (const float*)d_in[8];
  float* out = (float*)d_out;

  float2* Kws     = (float2*)d_ws;   // 4096 float2 = 32 KB
  float2* keff_br = Kws + LEN;       // 4096 float2 = 32 KB

  s4_kernelA1<<<LEN/256, 256, 0, stream>>>(Lre, Lim, Pre, Pim, Bre, Bim, Cre, Cim, Kws);
  s4_kernelA2<<<LEN/256, 256, 0, stream>>>(Kws, keff_br);

  const int rows = out_size / LEN;   // 16*256 = 4096
  s4_fftconv<<<rows/2, 256, 0, stream>>>(x, keff_br, out);
}

// Round 2
// 160.605 us; speedup vs baseline: 1.1324x; 1.1324x over previous
//
#include <hip/hip_runtime.h>
#include <math.h>

#define LEN 4096
#define NSTATE 64

__device__ inline float2 cmulf(float2 a, float2 b){
  return make_float2(a.x*b.x - a.y*b.y, a.x*b.y + a.y*b.x);
}

// ---------------- Setup kernel 1: K[k] via DPLR Cauchy sums (double precision) ----------------
// One wave (64 lanes) per frequency k; lane n handles DPLR term n; shfl_xor reduction.
__global__ __launch_bounds__(64)
void s4_kernelA1(const float* __restrict__ Lre, const float* __restrict__ Lim,
                 const float* __restrict__ Pre, const float* __restrict__ Pim,
                 const float* __restrict__ Bre, const float* __restrict__ Bim,
                 const float* __restrict__ Cre, const float* __restrict__ Cim,
                 float2* __restrict__ Kout) {
  const int k = blockIdx.x;
  const int n = threadIdx.x;   // 0..63

  double ang = -2.0 * M_PI * (double)k / (double)LEN;
  double orr = cos(ang), oi = sin(ang);
  double dr = 1.0 + orr, di = oi;
  double d2 = dr*dr + di*di;
  double nr = 1.0 - orr, ni = -oi;
  double inv_d2 = 1.0 / d2;
  // g = (2/step) * (1-O)/(1+O), step=0.001
  double gr = 2000.0 * (nr*dr + ni*di) * inv_d2;
  double gi = 2000.0 * (ni*dr - nr*di) * inv_d2;
  // c = 2/(1+O)
  double cr = 2.0 * dr * inv_d2, ci = -2.0 * di * inv_d2;

  // per-lane DPLR term
  double lr = Lre[n], li = Lim[n];
  double pr = Pre[n], pi = Pim[n];
  double br = Bre[n], bi = Bim[n];
  double qr = Cre[n], qi = Cim[n];
  double er = gr - lr, ei = gi - li;
  double inv_e2 = 1.0 / (er*er + ei*ei);
  double den_r = er * inv_e2, den_i = -ei * inv_e2;   // 1/(g-Lambda)
  double cbr = qr*br + qi*bi, cbi = qr*bi - qi*br;    // conj(C)*B
  double cpr = qr*pr + qi*pi, cpi = qr*pi - qi*pr;    // conj(C)*P
  double pbr = pr*br + pi*bi, pbi = pr*bi - pi*br;    // conj(P)*B
  double ppr = pr*pr + pi*pi;                          // conj(P)*P (real)

  double k00r = den_r*cbr - den_i*cbi, k00i = den_r*cbi + den_i*cbr;
  double k01r = den_r*cpr - den_i*cpi, k01i = den_r*cpi + den_i*cpr;
  double k10r = den_r*pbr - den_i*pbi, k10i = den_r*pbi + den_i*pbr;
  double k11r = den_r*ppr,             k11i = den_i*ppr;

  // wave butterfly reduction of the 8 partials
  #pragma unroll
  for (int off = 32; off >= 1; off >>= 1) {
    k00r += __shfl_xor(k00r, off); k00i += __shfl_xor(k00i, off);
    k01r += __shfl_xor(k01r, off); k01i += __shfl_xor(k01i, off);
    k10r += __shfl_xor(k10r, off); k10i += __shfl_xor(k10i, off);
    k11r += __shfl_xor(k11r, off); k11i += __shfl_xor(k11i, off);
  }

  if (n == 0) {
    // K = c * (k00 - k01 * k10 / (1 + k11))
    double ar = 1.0 + k11r, ai = k11i;
    double inv_a2 = 1.0 / (ar*ar + ai*ai);
    double ivr = ar*inv_a2, ivi = -ai*inv_a2;
    double mr = k01r*k10r - k01i*k10i, mi = k01r*k10i + k01i*k10r;
    double tr = mr*ivr - mi*ivi, ti = mr*ivi + mi*ivr;
    double sr = k00r - tr, si = k00i - ti;
    double Kr = cr*sr - ci*si, Ki = cr*si + ci*sr;
    Kout[k] = make_float2((float)Kr, (float)Ki);
  }
}

// ---------------- Setup kernel 2: Hermitian-symmetrize, scale by 1/L, base-4 digit-reverse ----------------
__global__ void s4_kernelA2(const float2* __restrict__ Kin, float2* __restrict__ keff_br) {
  int p = blockIdx.x * blockDim.x + threadIdx.x;
  if (p >= LEN) return;
  int k = 0, pp = p;
  #pragma unroll
  for (int i = 0; i < 6; ++i) { k = (k << 2) | (pp & 3); pp >>= 2; }
  int kneg = (LEN - k) & (LEN - 1);
  float2 a = Kin[k], b = Kin[kneg];
  // Keff = (K[k] + conj(K[L-k])) / 2, scaled by 1/L
  const float s = 0.5f / (float)LEN;
  keff_br[p] = make_float2(s * (a.x + b.x), s * (a.y - b.y));
}

// ---------------- Main kernel: per row-pair, fwd FFT (DIF r4) -> multiply -> inv FFT (DIT r4) ----------------
__launch_bounds__(256)
__global__ void s4_fftconv(const float* __restrict__ x, const float2* __restrict__ keff_br,
                           float* __restrict__ out) {
  __shared__ float2 X[LEN];
  const int t = threadIdx.x;
  const size_t base = (size_t)blockIdx.x * 2 * LEN;
  const float* x1 = x + base;
  const float* x2 = x1 + LEN;

  #pragma unroll
  for (int i = 0; i < 16; ++i) {
    int idx = t + 256*i;
    X[idx] = make_float2(x1[idx], x2[idx]);
  }
  __syncthreads();

  // forward DIF radix-4: natural order in -> base-4 digit-reversed out
  for (int n = LEN; n >= 4; n >>= 2) {
    const int q = n >> 2;
    const float fac = -6.28318530717958647692f / (float)n;
    #pragma unroll
    for (int it = 0; it < 4; ++it) {
      int m = t + 256*it;
      int j = m & (q - 1);
      int i0 = 4*m - 3*j;            // = block_base + j
      float2 a0 = X[i0], a1 = X[i0+q], a2 = X[i0+2*q], a3 = X[i0+3*q];
      float2 t0 = make_float2(a0.x+a2.x, a0.y+a2.y);
      float2 t1 = make_float2(a0.x-a2.x, a0.y-a2.y);
      float2 t2 = make_float2(a1.x+a3.x, a1.y+a3.y);
      float2 t3 = make_float2(a1.x-a3.x, a1.y-a3.y);
      float2 y0 = make_float2(t0.x+t2.x, t0.y+t2.y);
      float2 y1 = make_float2(t1.x+t3.y, t1.y-t3.x);  // t1 - i*t3
      float2 y2 = make_float2(t0.x-t2.x, t0.y-t2.y);
      float2 y3 = make_float2(t1.x-t3.y, t1.y+t3.x);  // t1 + i*t3
      float ang = fac * (float)j;
      float s1, c1;
      __sincosf(ang, &s1, &c1);
      float2 w1 = make_float2(c1, s1);
      float2 w2 = cmulf(w1, w1);
      float2 w3 = cmulf(w2, w1);
      X[i0]     = y0;
      X[i0+q]   = cmulf(y1, w1);
      X[i0+2*q] = cmulf(y2, w2);
      X[i0+3*q] = cmulf(y3, w3);
    }
    __syncthreads();
  }

  // pointwise multiply by Keff/L (digit-reversed order), fused with first inverse stage (n=4: j=0, w=1)
  #pragma unroll
  for (int it = 0; it < 4; ++it) {
    int m = t + 256*it;
    int i0 = 4*m;
    float2 u0 = cmulf(X[i0],   keff_br[i0]);
    float2 u1 = cmulf(X[i0+1], keff_br[i0+1]);
    float2 u2 = cmulf(X[i0+2], keff_br[i0+2]);
    float2 u3 = cmulf(X[i0+3], keff_br[i0+3]);
    float2 t0 = make_float2(u0.x+u2.x, u0.y+u2.y);
    float2 t1 = make_float2(u0.x-u2.x, u0.y-u2.y);
    float2 t2 = make_float2(u1.x+u3.x, u1.y+u3.y);
    float2 t3 = make_float2(u1.x-u3.x, u1.y-u3.y);
    X[i0]   = make_float2(t0.x+t2.x, t0.y+t2.y);   // a0
    X[i0+1] = make_float2(t1.x-t3.y, t1.y+t3.x);   // a1 = t1 + i*t3
    X[i0+2] = make_float2(t0.x-t2.x, t0.y-t2.y);   // a2
    X[i0+3] = make_float2(t1.x+t3.y, t1.y-t3.x);   // a3 = t1 - i*t3
  }
  __syncthreads();

  // remaining inverse DIT radix-4 stages: digit-reversed in -> natural out (un-normalized; 1/L folded into keff)
  for (int n = 16; n <= LEN; n <<= 2) {
    const int q = n >> 2;
    const float fac = 6.28318530717958647692f / (float)n;
    #pragma unroll
    for (int it = 0; it < 4; ++it) {
      int m = t + 256*it;
      int j = m & (q - 1);
      int i0 = 4*m - 3*j;
      float ang = fac * (float)j;
      float s1, c1;
      __sincosf(ang, &s1, &c1);
      float2 w1 = make_float2(c1, s1);
      float2 w2 = cmulf(w1, w1);
      float2 w3 = cmulf(w2, w1);
      float2 u0 = X[i0];
      float2 u1 = cmulf(X[i0+q],   w1);
      float2 u2 = cmulf(X[i0+2*q], w2);
      float2 u3 = cmulf(X[i0+3*q], w3);
      float2 t0 = make_float2(u0.x+u2.x, u0.y+u2.y);
      float2 t1 = make_float2(u0.x-u2.x, u0.y-u2.y);
      float2 t2 = make_float2(u1.x+u3.x, u1.y+u3.y);
      float2 t3 = make_float2(u1.x-u3.x, u1.y-u3.y);
      X[i0]     = make_float2(t0.x+t2.x, t0.y+t2.y);
      X[i0+q]   = make_float2(t1.x-t3.y, t1.y+t3.x);  // t1 + i*t3
      X[i0+2*q] = make_float2(t0.x-t2.x, t0.y-t2.y);
      X[i0+3*q] = make_float2(t1.x+t3.y, t1.y-t3.x);  // t1 - i*t3
    }
    __syncthreads();
  }

  float* o1 = out + base;
  float* o2 = o1 + LEN;
  #pragma unroll
  for (int i = 0; i < 16; ++i) {
    int idx = t + 256*i;
    float2 v = X[idx];
    o1[idx] = v.x;   // row 2b   (real part)
    o2[idx] = v.y;   // row 2b+1 (imag part)
  }
}

extern "C" void kernel_launch(void* const* d_in, const int* in_sizes, int n_in,
                              void* d_out, int out_size, void* d_ws, size_t ws_size,
                              hipStream_t stream) {
  const float* x   = (const float*)d_in[0];
  const float* Lre = (const float*)d_in[1];
  const float* Lim = (const float*)d_in[2];
  const float* Pre = (const float*)d_in[3];
  const float* Pim = (const float*)d_in[4];
  const float* Bre = (const float*)d_in[5];
  const float* Bim = (const float*)d_in[6];
  const float* Cre = (const float*)d_in[7];
  const float* Cim = (const float*)d_in[8];
  float* out = (float*)d_out;

  float2* Kws     = (float2*)d_ws;   // 4096 float2 = 32 KB
  float2* keff_br = Kws + LEN;       // 4096 float2 = 32 KB

  s4_kernelA1<<<LEN, 64, 0, stream>>>(Lre, Lim, Pre, Pim, Bre, Bim, Cre, Cim, Kws);
  s4_kernelA2<<<LEN/256, 256, 0, stream>>>(Kws, keff_br);

  const int rows = out_size / LEN;   // 16*256 = 4096
  s4_fftconv<<<rows/2, 256, 0, stream>>>(x, keff_br, out);
}

// Round 3
// 149.630 us; speedup vs baseline: 1.2155x; 1.0733x over previous
//
#include <hip/hip_runtime.h>
#include <math.h>

#define LEN 4096
#define NSTATE 64

__device__ inline float2 cmulf(float2 a, float2 b){
  return make_float2(a.x*b.x - a.y*b.y, a.x*b.y + a.y*b.x);
}
__device__ inline float2 cadd(float2 a, float2 b){ return make_float2(a.x+b.x, a.y+b.y); }
__device__ inline float2 csub(float2 a, float2 b){ return make_float2(a.x-b.x, a.y-b.y); }

// ---- 16-point DFT in registers, natural order in and out ----
// Forward: X[f] = sum_l v[l] * exp(-2*pi*i*f*l/16). INV=true: exp(+...).
// Two radix-4 DIF layers + compile-time digit reversal.
template<bool INV>
__device__ inline void dft16(float2 v[16]) {
  const float C1 = 0.923879532511286756f;   // cos(pi/8)
  const float S1 = 0.382683432365089772f;   // sin(pi/8)
  const float R  = 0.707106781186547524f;   // sqrt(2)/2
  const float sg = INV ? 1.0f : -1.0f;
  const float2 W1 = make_float2( C1,  sg*S1);
  const float2 W2 = make_float2( R,   sg*R );
  const float2 W3 = make_float2( S1,  sg*C1);
  const float2 W6 = make_float2(-R,   sg*R );
  const float2 W9 = make_float2(-C1, -sg*S1);

#define BFLY4(a0,a1,a2,a3, o0,o1,o2,o3) { \
    float2 t0 = cadd(a0,a2), t1 = csub(a0,a2); \
    float2 t2 = cadd(a1,a3), t3 = csub(a1,a3); \
    o0 = cadd(t0,t2); o2 = csub(t0,t2); \
    if (!INV) { o1 = make_float2(t1.x + t3.y, t1.y - t3.x); \
                o3 = make_float2(t1.x - t3.y, t1.y + t3.x); } \
    else      { o1 = make_float2(t1.x - t3.y, t1.y + t3.x); \
                o3 = make_float2(t1.x + t3.y, t1.y - t3.x); } }

  float2 z[16];
  // layer 1: groups j = 0..3 over elements j, j+4, j+8, j+12; twiddle W16^{j*k}
  BFLY4(v[0], v[4], v[8],  v[12], z[0], z[4], z[8],  z[12]);
  { float2 y0,y1,y2,y3; BFLY4(v[1], v[5], v[9],  v[13], y0,y1,y2,y3);
    z[1]=y0; z[5]=cmulf(y1,W1); z[9] =cmulf(y2,W2); z[13]=cmulf(y3,W3); }
  { float2 y0,y1,y2,y3; BFLY4(v[2], v[6], v[10], v[14], y0,y1,y2,y3);
    z[2]=y0; z[6]=cmulf(y1,W2);
    z[10]= INV ? make_float2(-y2.y, y2.x) : make_float2(y2.y, -y2.x);  // *W16^4 = -+i
    z[14]=cmulf(y3,W6); }
  { float2 y0,y1,y2,y3; BFLY4(v[3], v[7], v[11], v[15], y0,y1,y2,y3);
    z[3]=y0; z[7]=cmulf(y1,W3); z[11]=cmulf(y2,W6); z[15]=cmulf(y3,W9); }
  // layer 2: groups b = 0..3 over contiguous quads (no twiddle, q=1)
  float2 u[16];
  BFLY4(z[0], z[1], z[2], z[3],  u[0], u[1], u[2], u[3]);
  BFLY4(z[4], z[5], z[6], z[7],  u[4], u[5], u[6], u[7]);
  BFLY4(z[8], z[9], z[10],z[11], u[8], u[9], u[10],u[11]);
  BFLY4(z[12],z[13],z[14],z[15], u[12],u[13],u[14],u[15]);
  // natural order: X[f] = u[4*(f&3) + (f>>2)]
  #pragma unroll
  for (int f = 0; f < 16; ++f) v[f] = u[((f & 3) << 2) | (f >> 2)];
#undef BFLY4
}

// multiply v[k] *= w1^k (k = 1..15), log-depth power chain
__device__ inline void apply_tw(float2 v[16], float2 w1) {
  float2 w2  = cmulf(w1,w1);
  float2 w3  = cmulf(w2,w1);
  float2 w4  = cmulf(w2,w2);
  float2 w5  = cmulf(w4,w1), w6 = cmulf(w4,w2), w7 = cmulf(w4,w3);
  float2 w8  = cmulf(w4,w4);
  float2 w9  = cmulf(w8,w1), w10 = cmulf(w8,w2), w11 = cmulf(w8,w3);
  float2 w12 = cmulf(w8,w4), w13 = cmulf(w8,w5), w14 = cmulf(w8,w6), w15 = cmulf(w8,w7);
  v[1]=cmulf(v[1],w1);   v[2]=cmulf(v[2],w2);   v[3]=cmulf(v[3],w3);
  v[4]=cmulf(v[4],w4);   v[5]=cmulf(v[5],w5);   v[6]=cmulf(v[6],w6);
  v[7]=cmulf(v[7],w7);   v[8]=cmulf(v[8],w8);   v[9]=cmulf(v[9],w9);
  v[10]=cmulf(v[10],w10);v[11]=cmulf(v[11],w11);v[12]=cmulf(v[12],w12);
  v[13]=cmulf(v[13],w13);v[14]=cmulf(v[14],w14);v[15]=cmulf(v[15],w15);
}

// ---------------- Setup kernel 1: K[k] via DPLR Cauchy sums (double precision) ----------------
// One wave (64 lanes) per frequency k; lane n handles DPLR term n; shfl_xor reduction.
__global__ __launch_bounds__(64)
void s4_kernelA1(const float* __restrict__ Lre, const float* __restrict__ Lim,
                 const float* __restrict__ Pre, const float* __restrict__ Pim,
                 const float* __restrict__ Bre, const float* __restrict__ Bim,
                 const float* __restrict__ Cre, const float* __restrict__ Cim,
                 float2* __restrict__ Kout) {
  const int k = blockIdx.x;
  const int n = threadIdx.x;   // 0..63

  double ang = -2.0 * M_PI * (double)k / (double)LEN;
  double orr = cos(ang), oi = sin(ang);
  double dr = 1.0 + orr, di = oi;
  double d2 = dr*dr + di*di;
  double nr = 1.0 - orr, ni = -oi;
  double inv_d2 = 1.0 / d2;
  double gr = 2000.0 * (nr*dr + ni*di) * inv_d2;   // g = (2/step)*(1-O)/(1+O)
  double gi = 2000.0 * (ni*dr - nr*di) * inv_d2;
  double cr = 2.0 * dr * inv_d2, ci = -2.0 * di * inv_d2;  // c = 2/(1+O)

  double lr = Lre[n], li = Lim[n];
  double pr = Pre[n], pi = Pim[n];
  double br = Bre[n], bi = Bim[n];
  double qr = Cre[n], qi = Cim[n];
  double er = gr - lr, ei = gi - li;
  double inv_e2 = 1.0 / (er*er + ei*ei);
  double den_r = er * inv_e2, den_i = -ei * inv_e2;   // 1/(g-Lambda)
  double cbr = qr*br + qi*bi, cbi = qr*bi - qi*br;    // conj(C)*B
  double cpr = qr*pr + qi*pi, cpi = qr*pi - qi*pr;    // conj(C)*P
  double pbr = pr*br + pi*bi, pbi = pr*bi - pi*br;    // conj(P)*B
  double ppr = pr*pr + pi*pi;                          // conj(P)*P (real)

  double k00r = den_r*cbr - den_i*cbi, k00i = den_r*cbi + den_i*cbr;
  double k01r = den_r*cpr - den_i*cpi, k01i = den_r*cpi + den_i*cpr;
  double k10r = den_r*pbr - den_i*pbi, k10i = den_r*pbi + den_i*pbr;
  double k11r = den_r*ppr,             k11i = den_i*ppr;

  #pragma unroll
  for (int off = 32; off >= 1; off >>= 1) {
    k00r += __shfl_xor(k00r, off); k00i += __shfl_xor(k00i, off);
    k01r += __shfl_xor(k01r, off); k01i += __shfl_xor(k01i, off);
    k10r += __shfl_xor(k10r, off); k10i += __shfl_xor(k10i, off);
    k11r += __shfl_xor(k11r, off); k11i += __shfl_xor(k11i, off);
  }

  if (n == 0) {
    double ar = 1.0 + k11r, ai = k11i;
    double inv_a2 = 1.0 / (ar*ar + ai*ai);
    double ivr = ar*inv_a2, ivi = -ai*inv_a2;
    double mr = k01r*k10r - k01i*k10i, mi = k01r*k10i + k01i*k10r;
    double tr = mr*ivr - mi*ivi, ti = mr*ivi + mi*ivr;
    double sr = k00r - tr, si = k00i - ti;
    double Kr = cr*sr - ci*si, Ki = cr*si + ci*sr;
    Kout[k] = make_float2((float)Kr, (float)Ki);
  }
}

// ---------------- Setup kernel 2: Hermitian-symmetrize, scale by 1/L, base-16 digit-reverse ----------------
__global__ void s4_kernelA2(const float2* __restrict__ Kin, float2* __restrict__ keff_br) {
  int p = blockIdx.x * blockDim.x + threadIdx.x;
  if (p >= LEN) return;
  // 3-round radix-16 DIF leaves freq k at position p = reverse of k's base-16 digits
  int k = ((p & 15) << 8) | (p & 240) | (p >> 8);
  int kneg = (LEN - k) & (LEN - 1);
  float2 a = Kin[k], b = Kin[kneg];
  const float s = 0.5f / (float)LEN;   // Hermitian average + 1/L ifft normalization
  keff_br[p] = make_float2(s * (a.x + b.x), s * (a.y - b.y));
}

// ---------------- Main kernel: radix-16, 3 fwd + 3 inv rounds, 4 LDS round-trips ----------------
// LDS padded: phys(i) = i + (i>>4)  -> uniform bank histogram for strides 256, 16, 1.
#define PHYS(i) ((i) + ((i) >> 4))

__launch_bounds__(256)
__global__ void s4_fftconv(const float* __restrict__ x, const float2* __restrict__ keff_br,
                           float* __restrict__ out) {
  __shared__ float2 X[LEN + LEN/16];
  const int t = threadIdx.x;
  const size_t base = (size_t)blockIdx.x * 2 * LEN;
  const float* x1 = x + base;
  const float* x2 = x1 + LEN;

  float2 v[16];

  // ---- fwd round 1 (n=4096, q=256, j=t), fused with global load ----
  #pragma unroll
  for (int k = 0; k < 16; ++k)
    v[k] = make_float2(x1[t + 256*k], x2[t + 256*k]);
  dft16<false>(v);
  { float s_, c_;
    __sincosf(-1.5339807878856412e-3f * (float)t, &s_, &c_);   // -2*pi/4096 * t
    apply_tw(v, make_float2(c_, s_)); }
  #pragma unroll
  for (int k = 0; k < 16; ++k) { int i = t + 256*k; X[PHYS(i)] = v[k]; }
  __syncthreads();

  // ---- fwd round 2 (n=256, q=16, j=t&15) ----
  const int i0 = ((t >> 4) << 8) + (t & 15);
  #pragma unroll
  for (int k = 0; k < 16; ++k) { int i = i0 + 16*k; v[k] = X[PHYS(i)]; }
  dft16<false>(v);
  { float s_, c_;
    __sincosf(-2.4543692606170259e-2f * (float)(t & 15), &s_, &c_); // -2*pi/256 * j
    apply_tw(v, make_float2(c_, s_)); }
  #pragma unroll
  for (int k = 0; k < 16; ++k) { int i = i0 + 16*k; X[PHYS(i)] = v[k]; }
  __syncthreads();

  // ---- fwd round 3 (n=16, q=1, no twiddle) + pointwise mult + inv round 1, all in registers ----
  #pragma unroll
  for (int k = 0; k < 16; ++k) v[k] = X[PHYS(16*t + k)];
  dft16<false>(v);
  #pragma unroll
  for (int f = 0; f < 16; ++f) v[f] = cmulf(v[f], keff_br[16*t + f]);
  dft16<true>(v);
  #pragma unroll
  for (int l = 0; l < 16; ++l) { int i = 16*t + l; X[PHYS(i)] = v[l]; }
  __syncthreads();

  // ---- inv round 2 (n=256, q=16): conj twiddle BEFORE inverse butterfly ----
  #pragma unroll
  for (int k = 0; k < 16; ++k) { int i = i0 + 16*k; v[k] = X[PHYS(i)]; }
  { float s_, c_;
    __sincosf(2.4543692606170259e-2f * (float)(t & 15), &s_, &c_);
    apply_tw(v, make_float2(c_, s_)); }
  dft16<true>(v);
  #pragma unroll
  for (int k = 0; k < 16; ++k) { int i = i0 + 16*k; X[PHYS(i)] = v[k]; }
  __syncthreads();

  // ---- inv round 3 (n=4096, q=256), fused with global store ----
  #pragma unroll
  for (int k = 0; k < 16; ++k) v[k] = X[PHYS(t + 256*k)];
  { float s_, c_;
    __sincosf(1.5339807878856412e-3f * (float)t, &s_, &c_);
    apply_tw(v, make_float2(c_, s_)); }
  dft16<true>(v);
  float* o1 = out + base;
  float* o2 = o1 + LEN;
  #pragma unroll
  for (int l = 0; l < 16; ++l) {
    o1[t + 256*l] = v[l].x;   // row 2b
    o2[t + 256*l] = v[l].y;   // row 2b+1
  }
}

extern "C" void kernel_launch(void* const* d_in, const int* in_sizes, int n_in,
                              void* d_out, int out_size, void* d_ws, size_t ws_size,
                              hipStream_t stream) {
  const float* x   = (const float*)d_in[0];
  const float* Lre = (const float*)d_in[1];
  const float* Lim = (const float*)d_in[2];
  const float* Pre = (const float*)d_in[3];
  const float* Pim = (const float*)d_in[4];
  const float* Bre = (const float*)d_in[5];
  const float* Bim = (const float*)d_in[6];
  const float* Cre = (const float*)d_in[7];
  const float* Cim = (const float*)d_in[8];
  float* out = (float*)d_out;

  float2* Kws     = (float2*)d_ws;   // 4096 float2 = 32 KB
  float2* keff_br = Kws + LEN;       // 4096 float2 = 32 KB

  s4_kernelA1<<<LEN, 64, 0, stream>>>(Lre, Lim, Pre, Pim, Bre, Bim, Cre, Cim, Kws);
  s4_kernelA2<<<LEN/256, 256, 0, stream>>>(Kws, keff_br);

  const int rows = out_size / LEN;   // 16*256 = 4096
  s4_fftconv<<<rows/2, 256, 0, stream>>>(x, keff_br, out);
}

// Round 4
// 145.755 us; speedup vs baseline: 1.2478x; 1.0266x over previous
//
#include <hip/hip_runtime.h>
#include <math.h>

#define LEN 4096
#define NSTATE 64

__device__ inline float2 cmulf(float2 a, float2 b){
  return make_float2(a.x*b.x - a.y*b.y, a.x*b.y + a.y*b.x);
}
__device__ inline float2 cadd(float2 a, float2 b){ return make_float2(a.x+b.x, a.y+b.y); }
__device__ inline float2 csub(float2 a, float2 b){ return make_float2(a.x-b.x, a.y-b.y); }

// ---- 16-point DFT in registers, natural order in and out ----
template<bool INV>
__device__ inline void dft16(float2 v[16]) {
  const float C1 = 0.923879532511286756f;   // cos(pi/8)
  const float S1 = 0.382683432365089772f;   // sin(pi/8)
  const float R  = 0.707106781186547524f;   // sqrt(2)/2
  const float sg = INV ? 1.0f : -1.0f;
  const float2 W1 = make_float2( C1,  sg*S1);
  const float2 W2 = make_float2( R,   sg*R );
  const float2 W3 = make_float2( S1,  sg*C1);
  const float2 W6 = make_float2(-R,   sg*R );
  const float2 W9 = make_float2(-C1, -sg*S1);

#define BFLY4(a0,a1,a2,a3, o0,o1,o2,o3) { \
    float2 t0 = cadd(a0,a2), t1 = csub(a0,a2); \
    float2 t2 = cadd(a1,a3), t3 = csub(a1,a3); \
    o0 = cadd(t0,t2); o2 = csub(t0,t2); \
    if (!INV) { o1 = make_float2(t1.x + t3.y, t1.y - t3.x); \
                o3 = make_float2(t1.x - t3.y, t1.y + t3.x); } \
    else      { o1 = make_float2(t1.x - t3.y, t1.y + t3.x); \
                o3 = make_float2(t1.x + t3.y, t1.y - t3.x); } }

  float2 z[16];
  BFLY4(v[0], v[4], v[8],  v[12], z[0], z[4], z[8],  z[12]);
  { float2 y0,y1,y2,y3; BFLY4(v[1], v[5], v[9],  v[13], y0,y1,y2,y3);
    z[1]=y0; z[5]=cmulf(y1,W1); z[9] =cmulf(y2,W2); z[13]=cmulf(y3,W3); }
  { float2 y0,y1,y2,y3; BFLY4(v[2], v[6], v[10], v[14], y0,y1,y2,y3);
    z[2]=y0; z[6]=cmulf(y1,W2);
    z[10]= INV ? make_float2(-y2.y, y2.x) : make_float2(y2.y, -y2.x);  // *W16^4 = -+i
    z[14]=cmulf(y3,W6); }
  { float2 y0,y1,y2,y3; BFLY4(v[3], v[7], v[11], v[15], y0,y1,y2,y3);
    z[3]=y0; z[7]=cmulf(y1,W3); z[11]=cmulf(y2,W6); z[15]=cmulf(y3,W9); }
  float2 u[16];
  BFLY4(z[0], z[1], z[2], z[3],  u[0], u[1], u[2], u[3]);
  BFLY4(z[4], z[5], z[6], z[7],  u[4], u[5], u[6], u[7]);
  BFLY4(z[8], z[9], z[10],z[11], u[8], u[9], u[10],u[11]);
  BFLY4(z[12],z[13],z[14],z[15], u[12],u[13],u[14],u[15]);
  #pragma unroll
  for (int f = 0; f < 16; ++f) v[f] = u[((f & 3) << 2) | (f >> 2)];
#undef BFLY4
}

// multiply v[k] *= w1^k (k = 1..15), log-depth power chain
__device__ inline void apply_tw(float2 v[16], float2 w1) {
  float2 w2  = cmulf(w1,w1);
  float2 w3  = cmulf(w2,w1);
  float2 w4  = cmulf(w2,w2);
  float2 w5  = cmulf(w4,w1), w6 = cmulf(w4,w2), w7 = cmulf(w4,w3);
  float2 w8  = cmulf(w4,w4);
  float2 w9  = cmulf(w8,w1), w10 = cmulf(w8,w2), w11 = cmulf(w8,w3);
  float2 w12 = cmulf(w8,w4), w13 = cmulf(w8,w5), w14 = cmulf(w8,w6), w15 = cmulf(w8,w7);
  v[1]=cmulf(v[1],w1);   v[2]=cmulf(v[2],w2);   v[3]=cmulf(v[3],w3);
  v[4]=cmulf(v[4],w4);   v[5]=cmulf(v[5],w5);   v[6]=cmulf(v[6],w6);
  v[7]=cmulf(v[7],w7);   v[8]=cmulf(v[8],w8);   v[9]=cmulf(v[9],w9);
  v[10]=cmulf(v[10],w10);v[11]=cmulf(v[11],w11);v[12]=cmulf(v[12],w12);
  v[13]=cmulf(v[13],w13);v[14]=cmulf(v[14],w14);v[15]=cmulf(v[15],w15);
}

// ---------------- Setup kernel 1: K[k] via DPLR Cauchy sums (double precision) ----------------
__global__ __launch_bounds__(64)
void s4_kernelA1(const float* __restrict__ Lre, const float* __restrict__ Lim,
                 const float* __restrict__ Pre, const float* __restrict__ Pim,
                 const float* __restrict__ Bre, const float* __restrict__ Bim,
                 const float* __restrict__ Cre, const float* __restrict__ Cim,
                 float2* __restrict__ Kout) {
  const int k = blockIdx.x;
  const int n = threadIdx.x;   // 0..63

  double ang = -2.0 * M_PI * (double)k / (double)LEN;
  double orr = cos(ang), oi = sin(ang);
  double dr = 1.0 + orr, di = oi;
  double d2 = dr*dr + di*di;
  double nr = 1.0 - orr, ni = -oi;
  double inv_d2 = 1.0 / d2;
  double gr = 2000.0 * (nr*dr + ni*di) * inv_d2;   // g = (2/step)*(1-O)/(1+O)
  double gi = 2000.0 * (ni*dr - nr*di) * inv_d2;
  double cr = 2.0 * dr * inv_d2, ci = -2.0 * di * inv_d2;  // c = 2/(1+O)

  double lr = Lre[n], li = Lim[n];
  double pr = Pre[n], pi = Pim[n];
  double br = Bre[n], bi = Bim[n];
  double qr = Cre[n], qi = Cim[n];
  double er = gr - lr, ei = gi - li;
  double inv_e2 = 1.0 / (er*er + ei*ei);
  double den_r = er * inv_e2, den_i = -ei * inv_e2;   // 1/(g-Lambda)
  double cbr = qr*br + qi*bi, cbi = qr*bi - qi*br;    // conj(C)*B
  double cpr = qr*pr + qi*pi, cpi = qr*pi - qi*pr;    // conj(C)*P
  double pbr = pr*br + pi*bi, pbi = pr*bi - pi*br;    // conj(P)*B
  double ppr = pr*pr + pi*pi;                          // conj(P)*P (real)

  double k00r = den_r*cbr - den_i*cbi, k00i = den_r*cbi + den_i*cbr;
  double k01r = den_r*cpr - den_i*cpi, k01i = den_r*cpi + den_i*cpr;
  double k10r = den_r*pbr - den_i*pbi, k10i = den_r*pbi + den_i*pbr;
  double k11r = den_r*ppr,             k11i = den_i*ppr;

  #pragma unroll
  for (int off = 32; off >= 1; off >>= 1) {
    k00r += __shfl_xor(k00r, off); k00i += __shfl_xor(k00i, off);
    k01r += __shfl_xor(k01r, off); k01i += __shfl_xor(k01i, off);
    k10r += __shfl_xor(k10r, off); k10i += __shfl_xor(k10i, off);
    k11r += __shfl_xor(k11r, off); k11i += __shfl_xor(k11i, off);
  }

  if (n == 0) {
    double ar = 1.0 + k11r, ai = k11i;
    double inv_a2 = 1.0 / (ar*ar + ai*ai);
    double ivr = ar*inv_a2, ivi = -ai*inv_a2;
    double mr = k01r*k10r - k01i*k10i, mi = k01r*k10i + k01i*k10r;
    double tr = mr*ivr - mi*ivi, ti = mr*ivi + mi*ivr;
    double sr = k00r - tr, si = k00i - ti;
    double Kr = cr*sr - ci*si, Ki = cr*si + ci*sr;
    Kout[k] = make_float2((float)Kr, (float)Ki);
  }
}

// ---------------- Setup kernel 2: Hermitian-symmetrize, scale by 1/L, base-16 digit-reverse ----------------
__global__ void s4_kernelA2(const float2* __restrict__ Kin, float2* __restrict__ keff_br) {
  int p = blockIdx.x * blockDim.x + threadIdx.x;
  if (p >= LEN) return;
  int k = ((p & 15) << 8) | (p & 240) | (p >> 8);
  int kneg = (LEN - k) & (LEN - 1);
  float2 a = Kin[k], b = Kin[kneg];
  const float s = 0.5f / (float)LEN;   // Hermitian average + 1/L ifft normalization
  keff_br[p] = make_float2(s * (a.x + b.x), s * (a.y - b.y));
}

// ---------------- Main kernel: radix-16, 3 fwd + 3 inv rounds, 4 LDS round-trips ----------------
// LDS XOR swizzle (no padding -> 32768 B -> 5 blocks/CU):
//   phys(i) = i ^ ((i>>4)&15). Bank-pair index = phys mod 16.
//   stride-256 access (i=t+256k): phys%16 = (t&15)^((t>>4)&15) -> 16 distinct per 16-lane group
//   stride-16  access (i=i0+16k): phys%16 = (t&15)^k           -> 16 distinct per 16-lane group
//   stride-1   access (i=16t+k):  phys%16 = k^(t&15)           -> 16 distinct per 16-lane group
//   => <=2 lanes/bank per 32-lane half everywhere = conflict-free [m136].
#define PHYS(i) ((i) ^ (((i) >> 4) & 15))

__launch_bounds__(256)
__global__ void s4_fftconv(const float* __restrict__ x, const float2* __restrict__ keff_br,
                           float* __restrict__ out) {
  __shared__ float2 X[LEN];
  const int t = threadIdx.x;
  const size_t base = (size_t)blockIdx.x * 2 * LEN;
  const float* x1 = x + base;
  const float* x2 = x1 + LEN;

  // prefetch keff (16 float2 = 8 float4, contiguous 128B per thread) into registers
  // so the barrier-serialized middle section has no global-load dependency.
  float4 kk[8];
  { const float4* kp = (const float4*)(keff_br + 16*t);
    #pragma unroll
    for (int j = 0; j < 8; ++j) kk[j] = kp[j]; }

  float2 v[16];

  // ---- fwd round 1 (n=4096, q=256, j=t), fused with global load ----
  #pragma unroll
  for (int k = 0; k < 16; ++k)
    v[k] = make_float2(x1[t + 256*k], x2[t + 256*k]);
  dft16<false>(v);
  { float s_, c_;
    __sincosf(-1.5339807878856412e-3f * (float)t, &s_, &c_);   // -2*pi/4096 * t
    apply_tw(v, make_float2(c_, s_)); }
  #pragma unroll
  for (int k = 0; k < 16; ++k) { int i = t + 256*k; X[PHYS(i)] = v[k]; }
  __syncthreads();

  // ---- fwd round 2 (n=256, q=16, j=t&15) ----
  const int i0 = ((t >> 4) << 8) + (t & 15);
  #pragma unroll
  for (int k = 0; k < 16; ++k) { int i = i0 + 16*k; v[k] = X[PHYS(i)]; }
  dft16<false>(v);
  { float s_, c_;
    __sincosf(-2.4543692606170259e-2f * (float)(t & 15), &s_, &c_); // -2*pi/256 * j
    apply_tw(v, make_float2(c_, s_)); }
  #pragma unroll
  for (int k = 0; k < 16; ++k) { int i = i0 + 16*k; X[PHYS(i)] = v[k]; }
  __syncthreads();

  // ---- fwd round 3 (n=16, q=1) + pointwise mult (registers) + inv round 1 ----
  #pragma unroll
  for (int k = 0; k < 16; ++k) v[k] = X[PHYS(16*t + k)];
  dft16<false>(v);
  #pragma unroll
  for (int j = 0; j < 8; ++j) {
    v[2*j]   = cmulf(v[2*j],   make_float2(kk[j].x, kk[j].y));
    v[2*j+1] = cmulf(v[2*j+1], make_float2(kk[j].z, kk[j].w));
  }
  dft16<true>(v);
  #pragma unroll
  for (int l = 0; l < 16; ++l) { int i = 16*t + l; X[PHYS(i)] = v[l]; }
  __syncthreads();

  // ---- inv round 2 (n=256, q=16): conj twiddle BEFORE inverse butterfly ----
  #pragma unroll
  for (int k = 0; k < 16; ++k) { int i = i0 + 16*k; v[k] = X[PHYS(i)]; }
  { float s_, c_;
    __sincosf(2.4543692606170259e-2f * (float)(t & 15), &s_, &c_);
    apply_tw(v, make_float2(c_, s_)); }
  dft16<true>(v);
  #pragma unroll
  for (int k = 0; k < 16; ++k) { int i = i0 + 16*k; X[PHYS(i)] = v[k]; }
  __syncthreads();

  // ---- inv round 3 (n=4096, q=256), fused with global store ----
  #pragma unroll
  for (int k = 0; k < 16; ++k) v[k] = X[PHYS(t + 256*k)];
  { float s_, c_;
    __sincosf(1.5339807878856412e-3f * (float)t, &s_, &c_);
    apply_tw(v, make_float2(c_, s_)); }
  dft16<true>(v);
  float* o1 = out + base;
  float* o2 = o1 + LEN;
  #pragma unroll
  for (int l = 0; l < 16; ++l) {
    o1[t + 256*l] = v[l].x;   // row 2b
    o2[t + 256*l] = v[l].y;   // row 2b+1
  }
}

extern "C" void kernel_launch(void* const* d_in, const int* in_sizes, int n_in,
                              void* d_out, int out_size, void* d_ws, size_t ws_size,
                              hipStream_t stream) {
  const float* x   = (const float*)d_in[0];
  const float* Lre = (const float*)d_in[1];
  const float* Lim = (const float*)d_in[2];
  const float* Pre = (const float*)d_in[3];
  const float* Pim = (const float*)d_in[4];
  const float* Bre = (const float*)d_in[5];
  const float* Bim = (const float*)d_in[6];
  const float* Cre = (const float*)d_in[7];
  const float* Cim = (const float*)d_in[8];
  float* out = (float*)d_out;

  float2* Kws     = (float2*)d_ws;   // 4096 float2 = 32 KB
  float2* keff_br = Kws + LEN;       // 4096 float2 = 32 KB

  s4_kernelA1<<<LEN, 64, 0, stream>>>(Lre, Lim, Pre, Pim, Bre, Bim, Cre, Cim, Kws);
  s4_kernelA2<<<LEN/256, 256, 0, stream>>>(Kws, keff_br);

  const int rows = out_size / LEN;   // 16*256 = 4096
  s4_fftconv<<<rows/2, 256, 0, stream>>>(x, keff_br, out);
}